// Round 4
// baseline (228.410 us; speedup 1.0000x reference)
//
#include <hip/hip_runtime.h>
#include <math.h>

#define SS 1024
#define NC 8
#define BWD 170
#define THRESH 1e-4f

typedef unsigned long long ull;

__device__ __forceinline__ float2 cmul(float2 a, float2 b) {
    return make_float2(a.x * b.x - a.y * b.y, a.x * b.y + a.y * b.x);
}

// ---------------------------------------------------------------------------
// XOR bank swizzle for FFT LDS buffers: bijection on [0,1024), mixes bits 4-7
// into bits 0-3 so every Stockham write stage hits 16 distinct bank-pairs
// while stride-1 reads stay conflict-free.
// ---------------------------------------------------------------------------
#define XS(a) ((a) ^ (((a) >> 4) & 15))

// ---------------------------------------------------------------------------
// Pair-interleaved column map for Zf: column kx and its conjugate partner
// 1024-kx land in ADJACENT float2 slots, so the fft2 consumer reads both
// with one dense float4 per (y,m). Bijection on [0,1024):
//   0->0, 512->1, kx in [1,511] -> 2kx, kx in [513,1023] -> 2(1024-kx)+1.
// ---------------------------------------------------------------------------
__device__ __forceinline__ int cmap(int kx) {
    if (kx == 0) return 0;
    if (kx == 512) return 1;
    return (kx < 512) ? (kx << 1) : (((1024 - kx) << 1) | 1);
}

template <int DIR>
__device__ __forceinline__ void bfly4(const float2 v[4], float2 r[4]) {
    float2 a = v[0], b = v[1], c = v[2], d = v[3];
    float2 apc = make_float2(a.x + c.x, a.y + c.y);
    float2 amc = make_float2(a.x - c.x, a.y - c.y);
    float2 bpd = make_float2(b.x + d.x, b.y + d.y);
    float2 jb  = make_float2(-(b.y - d.y), b.x - d.x);   // i*(b-d)
    r[0] = make_float2(apc.x + bpd.x, apc.y + bpd.y);
    r[2] = make_float2(apc.x - bpd.x, apc.y - bpd.y);
    if (DIR == -1) {
        r[1] = make_float2(amc.x - jb.x, amc.y - jb.y);
        r[3] = make_float2(amc.x + jb.x, amc.y + jb.y);
    } else {
        r[1] = make_float2(amc.x + jb.x, amc.y + jb.y);
        r[3] = make_float2(amc.x - jb.x, amc.y - jb.y);
    }
}

// ---------------------------------------------------------------------------
// 1024-pt Stockham radix-4 over a 256-thread GROUP (t = thread-in-group),
// register-resident ends, INLINE twiddles. Stages 0-3 via LDS (XS swizzle);
// stage 4 (twiddle-free, thread-local) in registers. sb=true runs
// SINGLE-BUFFERED (A==B): each stage becomes write->sync->read->sync.
// NOTE: __syncthreads() is BLOCK-wide; when multiple groups share a block
// they must execute identical barrier sequences (all calls unconditional).
// On entry v[m] holds element (t+256m); on exit v[r] = element t+256r.
// ---------------------------------------------------------------------------
template <int DIR>
__device__ __forceinline__ void fft1024_reg(float2 v[4], float2* A, float2* B,
                                            int t, bool sb) {
    float2* dst = A;
    float2* alt = B;
    #pragma unroll
    for (int st = 0; st < 4; ++st) {
        int s = 1 << (2 * st);
        int k = t & ~(s - 1);
        float2 r[4];
        bfly4<DIR>(v, r);
        float rev = (float)k * (1.0f / 1024.0f);
        float2 w1 = make_float2(__builtin_amdgcn_cosf(rev),
                                (float)DIR * __builtin_amdgcn_sinf(rev));
        float2 w2 = cmul(w1, w1);
        float2 w3 = cmul(w2, w1);
        int base = t + 3 * k;
        dst[XS(base)]         = r[0];
        dst[XS(base + s)]     = cmul(r[1], w1);
        dst[XS(base + 2 * s)] = cmul(r[2], w2);
        dst[XS(base + 3 * s)] = cmul(r[3], w3);
        __syncthreads();
        v[0] = dst[XS(t)];
        v[1] = dst[XS(t + 256)];
        v[2] = dst[XS(t + 512)];
        v[3] = dst[XS(t + 768)];
        if (sb) __syncthreads();
        float2* tmp = dst; dst = alt; alt = tmp;
    }
    float2 r[4];
    bfly4<DIR>(v, r);   // stage 4: twiddle-free, thread-local
    v[0] = r[0]; v[1] = r[1]; v[2] = r[2]; v[3] = r[3];
}

// LDS padding for the H-blur row buffers (float units, stride-4 reads)
#define PIDX(r) ((r) + ((r) >> 5))

// ---------------------------------------------------------------------------
// Fused blur + alpha blend + pack + forward row FFT. Block = (channel, row).
// XCD-band swizzle keeps the 7-row V-blur halo in one XCD's L2.
// V-blur in registers, H-blur via one LDS row, alpha blend,
// pack Z = lms_e + i*fuse_e into bufA (XS layout), FFT, store from registers
// into the PAIR-INTERLEAVED cmap layout (stride-2 per wave; the mirror wave
// of the same block fills the other half of each line -> L2 write-combines).
// ---------------------------------------------------------------------------
__global__ __launch_bounds__(256) void blur_fft_kernel(
        const float* __restrict__ lms, const float* __restrict__ fuse,
        float2* __restrict__ Zf) {
    __shared__ float2 bufA[1024];      // handoff + FFT ping-pong partner
    __shared__ float2 smemB2[1068];    // aliases: rowl/rowf floats, FFT buffer
    float* rowl = (float*)smemB2;      // PIDX(col+3), col -3..1026
    float* rowf = rowl + 1068;
    int tid = threadIdx.x;
    int g = blockIdx.x;
    int c = g >> 10;
    int y = (g & 7) * 128 + ((g >> 3) & 127);   // XCD band swizzle
    const float* L = lms + ((size_t)c << 20);
    const float* F = fuse + ((size_t)c << 20);
    int x0 = tid << 2;

    // Gaussian weights (sigma=1, ks=7)
    double e1 = exp(-0.5), e2 = exp(-2.0), e3 = exp(-4.5);
    double sm = 1.0 + 2.0 * (e1 + e2 + e3);
    float w[7] = { (float)(e3 / sm), (float)(e2 / sm), (float)(e1 / sm),
                   (float)(1.0 / sm),
                   (float)(e1 / sm), (float)(e2 / sm), (float)(e3 / sm) };

    bool rowInt = (y >= BWD) && (y <= SS - 1 - BWD);
    bool skipLoads = rowInt && (tid >= 45) && (tid <= 210);
    bool doH = !rowInt || (tid <= 43) || (tid >= 212);

    float4 cl, cf;
    if (skipLoads) {
        cl = *(const float4*)&L[((size_t)y << 10) + x0];
        cf = *(const float4*)&F[((size_t)y << 10) + x0];
    } else {
        float4 lv[7], fv[7];
        #pragma unroll
        for (int r = 0; r < 7; ++r) {
            int gy = y - 3 + r;
            if (gy >= 0 && gy < SS) {
                lv[r] = *(const float4*)&L[((size_t)gy << 10) + x0];
                fv[r] = *(const float4*)&F[((size_t)gy << 10) + x0];
            } else {
                lv[r] = make_float4(0.f, 0.f, 0.f, 0.f);
                fv[r] = make_float4(0.f, 0.f, 0.f, 0.f);
            }
        }
        cl = lv[3]; cf = fv[3];
        #pragma unroll
        for (int j = 0; j < 4; ++j) {
            float a = 0.f, b = 0.f;
            #pragma unroll
            for (int r = 0; r < 7; ++r) {
                a += w[r] * (&lv[r].x)[j];
                b += w[r] * (&fv[r].x)[j];
            }
            rowl[PIDX(3 + x0 + j)] = a;
            rowf[PIDX(3 + x0 + j)] = b;
        }
    }
    if (tid < 3) {
        rowl[PIDX(tid)] = 0.f; rowf[PIDX(tid)] = 0.f;
        rowl[PIDX(1027 + tid)] = 0.f; rowf[PIDX(1027 + tid)] = 0.f;
    }
    __syncthreads();

    float bl[4] = {0.f, 0.f, 0.f, 0.f}, bf[4] = {0.f, 0.f, 0.f, 0.f};
    if (doH) {
        #pragma unroll
        for (int k = 0; k < 4; ++k) {
            float a = 0.f, b = 0.f;
            #pragma unroll
            for (int j = 0; j < 7; ++j) {
                a += w[j] * rowl[PIDX(x0 + k + j)];
                b += w[j] * rowf[PIDX(x0 + k + j)];
            }
            bl[k] = a; bf[k] = b;
        }
    }
    int gyv = (y < BWD) ? y : ((SS - 1 - y) < BWD ? (SS - 1 - y) : -1);
    #pragma unroll
    for (int k = 0; k < 4; ++k) {
        int x = x0 + k;
        int gx = (x < BWD) ? x : ((SS - 1 - x) < BWD ? (SS - 1 - x) : -1);
        int m = gyv > gx ? gyv : gx;
        float a = (m >= 0) ? (float)m / (float)BWD : 1.0f;
        bufA[XS(x)] = make_float2(a * (&cl.x)[k] + (1.0f - a) * bl[k],
                                  a * (&cf.x)[k] + (1.0f - a) * bf[k]);
    }
    __syncthreads();   // bufA handoff ready; rowl/rowf reads done

    float2 v[4];
    #pragma unroll
    for (int m = 0; m < 4; ++m) v[m] = bufA[XS(tid + (m << 8))];
    fft1024_reg<-1>(v, smemB2, bufA, tid, false);

    float2* Zrow = Zf + (((size_t)c << 20) + ((size_t)y << 10));
    #pragma unroll
    for (int r = 0; r < 4; ++r) Zrow[cmap(tid + (r << 8))] = v[r];
}

// ---------------------------------------------------------------------------
// Fused second forward FFT + Wiener + first inverse FFT (along ky).
// Block = 512 threads = TWO independent 256-thread groups sharing one
// conjugate column pair (u, 1024-u) of a channel pair p:
//   group 0: fwd combo0 (row0,ch0) -> rb0, fwd combo2 (row1,ch0) -> rb2 (sb),
//            Wiener o=0, inverse o=0 (scratch rb0/rb2)
//   group 1: fwd combo1 (row0,ch1) -> rb1, fwd combo3 (row1,ch1) -> rb3 (sb),
//            Wiener o=1, inverse o=1 (scratch rb1/rb3)
// Critical path 6 serial FFTs -> ~3.3; LDS stays 32KB (4 result buffers);
// 4 blocks/CU x 8 waves = 100% static occupancy. All barriers unconditional
// and identical across groups (phase1 dbuf, phase2 sb, 2 explicit).
// ---------------------------------------------------------------------------
__global__ __launch_bounds__(512, 8) void fft2_wiener_kernel(
        const float2* __restrict__ Z, float2* __restrict__ Wb) {
    __shared__ float2 resbuf[4][1024];
    int tid = threadIdx.x;
    int grp = tid >> 8;               // 0,1 = channel within pair
    int t = tid & 255;
    int p = blockIdx.x >> 9;          // channel pair 0..3
    int b0 = blockIdx.x & 511;
    int i = ((b0 & 7) << 6) | (b0 >> 3);   // chunked XCD swizzle (64/chunk)
    int rows[2];
    rows[0] = (i == 0) ? 0 : i;
    rows[1] = (i == 0) ? 512 : 1024 - i;
    bool selfp = (i == 0);
    int slot = (i == 0) ? 0 : (i << 1);

    // group grp loads channel 2p+grp: float4 gives BOTH rows of the pair
    const float2* Zp = Z + ((size_t)(2 * p + grp) << 20);
    float4 q[4];
    #pragma unroll
    for (int m = 0; m < 4; ++m)
        q[m] = *(const float4*)&Zp[((size_t)(t + (m << 8)) << 10) + slot];

    float2 v[4];
    // phase 1: combo grp = (row0, ch grp) -> resbuf[grp]; scratch rb[2+grp]
    #pragma unroll
    for (int m = 0; m < 4; ++m) v[m] = make_float2(q[m].x, q[m].y);
    fft1024_reg<-1>(v, resbuf[2 + grp], resbuf[grp], t, false);
    #pragma unroll
    for (int r = 0; r < 4; ++r) resbuf[grp][XS(t + (r << 8))] = v[r];
    // phase 2: combo 2+grp = (row1, ch grp) -> resbuf[2+grp], single-buffered
    #pragma unroll
    for (int m = 0; m < 4; ++m) v[m] = make_float2(q[m].z, q[m].w);
    fft1024_reg<-1>(v, resbuf[2 + grp], resbuf[2 + grp], t, true);
    #pragma unroll
    for (int r = 0; r < 4; ++r) resbuf[2 + grp][XS(t + (r << 8))] = v[r];
    __syncthreads();   // all 4 forward results visible to both groups

    // Wiener for o = grp  (resbuf[combo] with combo = rowIdx*2 + ch)
    float2 gi[4];
    {
        int o = grp;
        int u = rows[o];
        int po = selfp ? o : (1 - o);      // partner row's slot base
        float cu = __builtin_amdgcn_cosf((float)u * (1.0f / 1024.0f));
        float c2u = 2.0f * cu * cu - 1.0f;
        float hu = 2.0f + 2.0f * cu;
        #pragma unroll
        for (int j = 0; j < 4; ++j) {
            int vv = t + (j << 8);
            int vn = (1024 - vv) & 1023;
            float cv = __builtin_amdgcn_cosf((float)vv * (1.0f / 1024.0f));
            float c2v = 2.0f * cv * cv - 1.0f;
            float hv = 2.0f + 2.0f * cv;
            float grad = (2.0f - 2.0f * c2v) * hu * hu +
                         (2.0f - 2.0f * c2u) * hv * hv;
            float regs = 5.0f + 5.0f * grad;
            float G0x, G0y, G1x, G1y;
            #pragma unroll
            for (int c = 0; c < 2; ++c) {
                float2 a = resbuf[o * 2 + c][XS(vv)];
                float2 b = resbuf[po * 2 + c][XS(vn)];
                float Lx = 0.5f * (a.x + b.x), Ly = 0.5f * (a.y - b.y);
                float Fx = 0.5f * (a.y + b.y), Fy = -0.5f * (a.x - b.x);
                float inv = 1.0f / (Fx * Fx + Fy * Fy + regs);
                float nx = (Fx * Lx + Fy * Ly) * inv;   // conj(F)*L
                float ny = (Fx * Ly - Fy * Lx) * inv;
                if (c == 0) { G0x = nx; G0y = ny; } else { G1x = nx; G1y = ny; }
            }
            gi[j] = make_float2(G0x - G1y, G0y + G1x);
        }
    }
    __syncthreads();   // all resbuf reads complete; buffers reusable

    // inverse FFT along ky for row rows[grp]; disjoint scratch per group
    fft1024_reg<1>(gi, resbuf[grp], resbuf[2 + grp], t, false);
    const float isc = 1.0f / 1024.0f;
    float2* go = Wb + (((size_t)p << 20) + ((size_t)rows[grp] << 10));
    #pragma unroll
    for (int r = 0; r < 4; ++r)
        go[t + (r << 8)] = make_float2(gi[r].x * isc, gi[r].y * isc);
}

// ---------------------------------------------------------------------------
// Final inverse pass: block = 512 threads = 2 groups, each owning one of two
// adjacent output rows (y0+grp) read via dense float4 column loads of
// Wb[p][kx][y0..y0+1] (both groups load the same lines; L1 absorbs the dup).
// Per-group private 16KB ping-pong (32KB total -> 100% static occupancy).
// Register row FFT, fused 1/N scale + fftshift + threshold + split + PER-WAVE
// argmax to private slots bm[ch*4096 + y*4 + wave-in-group]; no cross-group
// coupling outside the (unconditional, identical) FFT barriers.
// ---------------------------------------------------------------------------
__global__ __launch_bounds__(512, 8) void ifft_final_kernel(
        const float2* __restrict__ Wd, float* __restrict__ psf,
        ull* __restrict__ bm) {
    __shared__ float2 buf[2][2][1024];
    int tid = threadIdx.x;
    int grp = tid >> 8;
    int t = tid & 255;
    int wvloc = (tid >> 6) & 3;        // wave index within group
    int p = blockIdx.x >> 9;           // grid 2048: 4 planes x 512
    int b0 = blockIdx.x & 511;
    int y0 = (((b0 & 7) << 6) | (b0 >> 3)) << 1;   // chunked swizzle, 2 rows
    int y = y0 + grp;
    const float2* g = Wd + (((size_t)p << 20) + y0);
    float4 q[4];
    #pragma unroll
    for (int m = 0; m < 4; ++m)
        q[m] = *(const float4*)&g[(size_t)(t + (m << 8)) << 10];

    float2 v[4];
    #pragma unroll
    for (int m = 0; m < 4; ++m)
        v[m] = grp ? make_float2(q[m].z, q[m].w)
                   : make_float2(q[m].x, q[m].y);
    fft1024_reg<1>(v, buf[grp][0], buf[grp][1], t, false);

    const float sc = 1.0f / 1024.0f;
    int oy = (y + 512) & 1023;
    float* p0 = psf + (((size_t)(2 * p) << 20) + ((size_t)oy << 10));
    float* p1 = p0 + (1u << 20);
    ull e0 = 0, e1 = 0;
    #pragma unroll
    for (int r = 0; r < 4; ++r) {
        int k = t + (r << 8);
        float re = v[r].x * sc; re = (re < THRESH) ? 0.0f : re;
        float im = v[r].y * sc; im = (im < THRESH) ? 0.0f : im;
        int ox = (k + 512) & 1023;
        p0[ox] = re;
        p1[ox] = im;
        unsigned int idx = ((unsigned int)oy << 10) | (unsigned int)ox;
        ull c0 = ((ull)__float_as_uint(re) << 32) | (ull)(0xFFFFFFFFu - idx);
        ull c1 = ((ull)__float_as_uint(im) << 32) | (ull)(0xFFFFFFFFu - idx);
        e0 = c0 > e0 ? c0 : e0;
        e1 = c1 > e1 ? c1 : e1;
    }
    #pragma unroll
    for (int off = 32; off > 0; off >>= 1) {
        ull o0 = __shfl_down(e0, off);
        ull o1 = __shfl_down(e1, off);
        e0 = o0 > e0 ? o0 : e0;
        e1 = o1 > e1 ? o1 : e1;
    }
    if ((tid & 63) == 0) {
        bm[((size_t)(2 * p) << 12) + (y << 2) + wvloc] = e0;
        bm[((size_t)(2 * p + 1) << 12) + (y << 2) + wvloc] = e1;
    }
}

// ---------------------------------------------------------------------------
// Per-channel argmax finish (reduce 4096 per-wave maxima) + crop 41x41
// (dynamic_slice clamp semantics) + normalize. One block per channel.
// ---------------------------------------------------------------------------
__global__ __launch_bounds__(256) void crop_kernel(
        const float* __restrict__ psf, const ull* __restrict__ bm,
        float* __restrict__ out) {
    int c = blockIdx.x;
    __shared__ ull rmax[256];
    __shared__ float red[256];
    int tid = threadIdx.x;
    ull e = 0;
    for (int i = tid; i < 4096; i += 256) {
        ull v = bm[((size_t)c << 12) + i];
        e = v > e ? v : e;
    }
    rmax[tid] = e;
    __syncthreads();
    for (int s2 = 128; s2 > 0; s2 >>= 1) {
        if (tid < s2) { ull a = rmax[tid], b = rmax[tid + s2]; rmax[tid] = a > b ? a : b; }
        __syncthreads();
    }
    unsigned int bidx = 0xFFFFFFFFu - (unsigned int)(rmax[0] & 0xFFFFFFFFull);
    int row = (int)(bidx >> 10), col = (int)(bidx & 1023);
    int r0 = row - 20; if (r0 < 0) r0 = 0; if (r0 > SS - 41) r0 = SS - 41;
    int c0 = col - 20; if (c0 < 0) c0 = 0; if (c0 > SS - 41) c0 = SS - 41;
    const float* p = psf + ((size_t)c << 20);
    float local = 0.0f;
    for (int i = tid; i < 1681; i += 256) {
        int rr = i / 41, cc = i - rr * 41;
        local += p[(size_t)(r0 + rr) * SS + c0 + cc];
    }
    red[tid] = local;
    __syncthreads();
    for (int s2 = 128; s2 > 0; s2 >>= 1) {
        if (tid < s2) red[tid] += red[tid + s2];
        __syncthreads();
    }
    float inv = 1.0f / red[0];
    for (int i = tid; i < 1681; i += 256) {
        int rr = i / 41, cc = i - rr * 41;
        out[c * 1681 + i] = p[(size_t)(r0 + rr) * SS + c0 + cc] * inv;
    }
}

// ---------------------------------------------------------------------------
extern "C" void kernel_launch(void* const* d_in, const int* in_sizes, int n_in,
                              void* d_out, int out_size, void* d_ws,
                              size_t ws_size, hipStream_t stream) {
    const float* lms = (const float*)d_in[0];
    const float* fuse = (const float*)d_in[1];
    char* ws = (char*)d_ws;
    float2* Zf = (float2*)ws;                                   // 64 MB: 8 planes
    float2* Wb = (float2*)(ws + ((size_t)64 << 20));            // 32 MB: 4 planes
    float* psf = (float*)ws;                                    // 32 MB, reuses Zf
    ull* bm = (ull*)(ws + ((size_t)33 << 20));                  // 256 KB, dead Zf region
    float* outp = (float*)d_out;

    // 1. fused blur + pack + forward row-FFT -> Zf[c][y][cmap(kx)]
    blur_fft_kernel<<<8192, 256, 0, stream>>>(lms, fuse, Zf);
    // 2. fused col-FFT + Wiener + inverse-ky-FFT, 2 parallel groups/block
    fft2_wiener_kernel<<<2048, 512, 0, stream>>>(Zf, Wb);
    // 3. inverse kx-FFT (2 parallel rows/block) + shift/threshold/argmax
    ifft_final_kernel<<<2048, 512, 0, stream>>>(Wb, psf, bm);
    // 4. argmax finish + crop/normalize
    crop_kernel<<<8, 256, 0, stream>>>(psf, bm, outp);
}

// Round 5
// 207.947 us; speedup vs baseline: 1.0984x; 1.0984x over previous
//
#include <hip/hip_runtime.h>
#include <math.h>

#define SS 1024
#define NC 8
#define BWD 170
#define THRESH 1e-4f

typedef unsigned long long ull;

__device__ __forceinline__ float2 cmul(float2 a, float2 b) {
    return make_float2(a.x * b.x - a.y * b.y, a.x * b.y + a.y * b.x);
}

// ---------------------------------------------------------------------------
// XOR bank swizzle for FFT LDS buffers: bijection on [0,1024), mixes bits 4-7
// into bits 0-3 so every Stockham write stage hits 16 distinct bank-pairs
// while stride-1 reads stay conflict-free.
// ---------------------------------------------------------------------------
#define XS(a) ((a) ^ (((a) >> 4) & 15))

// ---------------------------------------------------------------------------
// Pair-interleaved column map for Zf: column kx and its conjugate partner
// 1024-kx land in ADJACENT float2 slots, so the fft2 consumer reads both
// with one dense float4 per (y,m). Bijection on [0,1024):
//   0->0, 512->1, kx in [1,511] -> 2kx, kx in [513,1023] -> 2(1024-kx)+1.
// ---------------------------------------------------------------------------
__device__ __forceinline__ int cmap(int kx) {
    if (kx == 0) return 0;
    if (kx == 512) return 1;
    return (kx < 512) ? (kx << 1) : (((1024 - kx) << 1) | 1);
}

template <int DIR>
__device__ __forceinline__ void bfly4(const float2 v[4], float2 r[4]) {
    float2 a = v[0], b = v[1], c = v[2], d = v[3];
    float2 apc = make_float2(a.x + c.x, a.y + c.y);
    float2 amc = make_float2(a.x - c.x, a.y - c.y);
    float2 bpd = make_float2(b.x + d.x, b.y + d.y);
    float2 jb  = make_float2(-(b.y - d.y), b.x - d.x);   // i*(b-d)
    r[0] = make_float2(apc.x + bpd.x, apc.y + bpd.y);
    r[2] = make_float2(apc.x - bpd.x, apc.y - bpd.y);
    if (DIR == -1) {
        r[1] = make_float2(amc.x - jb.x, amc.y - jb.y);
        r[3] = make_float2(amc.x + jb.x, amc.y + jb.y);
    } else {
        r[1] = make_float2(amc.x + jb.x, amc.y + jb.y);
        r[3] = make_float2(amc.x - jb.x, amc.y - jb.y);
    }
}

// ---------------------------------------------------------------------------
// 1024-pt Stockham radix-4 over a 256-thread GROUP (t = thread-in-group),
// register-resident ends, INLINE twiddles. Stages 0-3 via LDS (XS swizzle);
// stage 4 (twiddle-free, thread-local) in registers. sb=true runs
// SINGLE-BUFFERED (A==B): each stage becomes write->sync->read->sync.
// NOTE: __syncthreads() is BLOCK-wide; when multiple groups share a block
// they must execute identical barrier sequences (all calls unconditional).
// On entry v[m] holds element (t+256m); on exit v[r] = element t+256r.
// ---------------------------------------------------------------------------
template <int DIR>
__device__ __forceinline__ void fft1024_reg(float2 v[4], float2* A, float2* B,
                                            int t, bool sb) {
    float2* dst = A;
    float2* alt = B;
    #pragma unroll
    for (int st = 0; st < 4; ++st) {
        int s = 1 << (2 * st);
        int k = t & ~(s - 1);
        float2 r[4];
        bfly4<DIR>(v, r);
        float rev = (float)k * (1.0f / 1024.0f);
        float2 w1 = make_float2(__builtin_amdgcn_cosf(rev),
                                (float)DIR * __builtin_amdgcn_sinf(rev));
        float2 w2 = cmul(w1, w1);
        float2 w3 = cmul(w2, w1);
        int base = t + 3 * k;
        dst[XS(base)]         = r[0];
        dst[XS(base + s)]     = cmul(r[1], w1);
        dst[XS(base + 2 * s)] = cmul(r[2], w2);
        dst[XS(base + 3 * s)] = cmul(r[3], w3);
        __syncthreads();
        v[0] = dst[XS(t)];
        v[1] = dst[XS(t + 256)];
        v[2] = dst[XS(t + 512)];
        v[3] = dst[XS(t + 768)];
        if (sb) __syncthreads();
        float2* tmp = dst; dst = alt; alt = tmp;
    }
    float2 r[4];
    bfly4<DIR>(v, r);   // stage 4: twiddle-free, thread-local
    v[0] = r[0]; v[1] = r[1]; v[2] = r[2]; v[3] = r[3];
}

// LDS padding for the H-blur row buffers (float units, stride-4 reads)
#define PIDX(r) ((r) + ((r) >> 5))

// ---------------------------------------------------------------------------
// Fused blur + alpha blend + pack + forward row FFT. Block = (channel, row).
// XCD-band swizzle keeps the 7-row V-blur halo in one XCD's L2.
// V-blur in registers, H-blur via one LDS row, alpha blend,
// pack Z = lms_e + i*fuse_e into bufA (XS layout), FFT, store from registers
// into the PAIR-INTERLEAVED cmap layout (stride-2 per wave; the mirror wave
// of the same block fills the other half of each line -> L2 write-combines).
// ---------------------------------------------------------------------------
__global__ __launch_bounds__(256) void blur_fft_kernel(
        const float* __restrict__ lms, const float* __restrict__ fuse,
        float2* __restrict__ Zf) {
    __shared__ float2 bufA[1024];      // handoff + FFT ping-pong partner
    __shared__ float2 smemB2[1068];    // aliases: rowl/rowf floats, FFT buffer
    float* rowl = (float*)smemB2;      // PIDX(col+3), col -3..1026
    float* rowf = rowl + 1068;
    int tid = threadIdx.x;
    int g = blockIdx.x;
    int c = g >> 10;
    int y = (g & 7) * 128 + ((g >> 3) & 127);   // XCD band swizzle
    const float* L = lms + ((size_t)c << 20);
    const float* F = fuse + ((size_t)c << 20);
    int x0 = tid << 2;

    // Gaussian weights (sigma=1, ks=7)
    double e1 = exp(-0.5), e2 = exp(-2.0), e3 = exp(-4.5);
    double sm = 1.0 + 2.0 * (e1 + e2 + e3);
    float w[7] = { (float)(e3 / sm), (float)(e2 / sm), (float)(e1 / sm),
                   (float)(1.0 / sm),
                   (float)(e1 / sm), (float)(e2 / sm), (float)(e3 / sm) };

    bool rowInt = (y >= BWD) && (y <= SS - 1 - BWD);
    bool skipLoads = rowInt && (tid >= 45) && (tid <= 210);
    bool doH = !rowInt || (tid <= 43) || (tid >= 212);

    float4 cl, cf;
    if (skipLoads) {
        cl = *(const float4*)&L[((size_t)y << 10) + x0];
        cf = *(const float4*)&F[((size_t)y << 10) + x0];
    } else {
        float4 lv[7], fv[7];
        #pragma unroll
        for (int r = 0; r < 7; ++r) {
            int gy = y - 3 + r;
            if (gy >= 0 && gy < SS) {
                lv[r] = *(const float4*)&L[((size_t)gy << 10) + x0];
                fv[r] = *(const float4*)&F[((size_t)gy << 10) + x0];
            } else {
                lv[r] = make_float4(0.f, 0.f, 0.f, 0.f);
                fv[r] = make_float4(0.f, 0.f, 0.f, 0.f);
            }
        }
        cl = lv[3]; cf = fv[3];
        #pragma unroll
        for (int j = 0; j < 4; ++j) {
            float a = 0.f, b = 0.f;
            #pragma unroll
            for (int r = 0; r < 7; ++r) {
                a += w[r] * (&lv[r].x)[j];
                b += w[r] * (&fv[r].x)[j];
            }
            rowl[PIDX(3 + x0 + j)] = a;
            rowf[PIDX(3 + x0 + j)] = b;
        }
    }
    if (tid < 3) {
        rowl[PIDX(tid)] = 0.f; rowf[PIDX(tid)] = 0.f;
        rowl[PIDX(1027 + tid)] = 0.f; rowf[PIDX(1027 + tid)] = 0.f;
    }
    __syncthreads();

    float bl[4] = {0.f, 0.f, 0.f, 0.f}, bf[4] = {0.f, 0.f, 0.f, 0.f};
    if (doH) {
        #pragma unroll
        for (int k = 0; k < 4; ++k) {
            float a = 0.f, b = 0.f;
            #pragma unroll
            for (int j = 0; j < 7; ++j) {
                a += w[j] * rowl[PIDX(x0 + k + j)];
                b += w[j] * rowf[PIDX(x0 + k + j)];
            }
            bl[k] = a; bf[k] = b;
        }
    }
    int gyv = (y < BWD) ? y : ((SS - 1 - y) < BWD ? (SS - 1 - y) : -1);
    #pragma unroll
    for (int k = 0; k < 4; ++k) {
        int x = x0 + k;
        int gx = (x < BWD) ? x : ((SS - 1 - x) < BWD ? (SS - 1 - x) : -1);
        int m = gyv > gx ? gyv : gx;
        float a = (m >= 0) ? (float)m / (float)BWD : 1.0f;
        bufA[XS(x)] = make_float2(a * (&cl.x)[k] + (1.0f - a) * bl[k],
                                  a * (&cf.x)[k] + (1.0f - a) * bf[k]);
    }
    __syncthreads();   // bufA handoff ready; rowl/rowf reads done

    float2 v[4];
    #pragma unroll
    for (int m = 0; m < 4; ++m) v[m] = bufA[XS(tid + (m << 8))];
    fft1024_reg<-1>(v, smemB2, bufA, tid, false);

    float2* Zrow = Zf + (((size_t)c << 20) + ((size_t)y << 10));
    #pragma unroll
    for (int r = 0; r < 4; ++r) Zrow[cmap(tid + (r << 8))] = v[r];
}

// ---------------------------------------------------------------------------
// Fused second forward FFT + Wiener + first inverse FFT (along ky).
// Block = 512 threads = TWO independent 256-thread groups sharing one
// conjugate column pair (u, 1024-u) of a channel pair p:
//   group 0: fwd combo0 (row0,ch0) -> rb0, fwd combo2 (row1,ch0) -> rb2 (sb),
//            Wiener o=0, inverse o=0 (scratch rb0/rb2)
//   group 1: fwd combo1 (row0,ch1) -> rb1, fwd combo3 (row1,ch1) -> rb3 (sb),
//            Wiener o=1, inverse o=1 (scratch rb1/rb3)
// Critical path 6 serial FFTs -> ~3.3; LDS stays 32KB (4 result buffers).
// NO launch_bounds occupancy pin (R4 post-mortem: (512,8) forced VGPR=32 ->
// scratch spills -> +230MB HBM traffic). Register pressure eased by
// consuming each float4's (x,y) half immediately; only (z,w) kept (nq).
// All barriers unconditional and identical across groups.
// ---------------------------------------------------------------------------
__global__ __launch_bounds__(512) void fft2_wiener_kernel(
        const float2* __restrict__ Z, float2* __restrict__ Wb) {
    __shared__ float2 resbuf[4][1024];
    int tid = threadIdx.x;
    int grp = tid >> 8;               // 0,1 = channel within pair
    int t = tid & 255;
    int p = blockIdx.x >> 9;          // channel pair 0..3
    int b0 = blockIdx.x & 511;
    int i = ((b0 & 7) << 6) | (b0 >> 3);   // chunked XCD swizzle (64/chunk)
    int rows[2];
    rows[0] = (i == 0) ? 0 : i;
    rows[1] = (i == 0) ? 512 : 1024 - i;
    bool selfp = (i == 0);
    int slot = (i == 0) ? 0 : (i << 1);

    // group grp loads channel 2p+grp: float4 gives BOTH rows of the pair;
    // (x,y) -> v (phase 1 input), (z,w) -> nq (phase 2 input, 8 regs held)
    const float2* Zp = Z + ((size_t)(2 * p + grp) << 20);
    float2 v[4], nq[4];
    #pragma unroll
    for (int m = 0; m < 4; ++m) {
        float4 qq = *(const float4*)&Zp[((size_t)(t + (m << 8)) << 10) + slot];
        v[m] = make_float2(qq.x, qq.y);
        nq[m] = make_float2(qq.z, qq.w);
    }

    // phase 1: combo grp = (row0, ch grp) -> resbuf[grp]; scratch rb[2+grp]
    fft1024_reg<-1>(v, resbuf[2 + grp], resbuf[grp], t, false);
    #pragma unroll
    for (int r = 0; r < 4; ++r) resbuf[grp][XS(t + (r << 8))] = v[r];
    // phase 2: combo 2+grp = (row1, ch grp) -> resbuf[2+grp], single-buffered
    fft1024_reg<-1>(nq, resbuf[2 + grp], resbuf[2 + grp], t, true);
    #pragma unroll
    for (int r = 0; r < 4; ++r) resbuf[2 + grp][XS(t + (r << 8))] = nq[r];
    __syncthreads();   // all 4 forward results visible to both groups

    // Wiener for o = grp  (resbuf[combo] with combo = rowIdx*2 + ch)
    float2 gi[4];
    {
        int o = grp;
        int u = rows[o];
        int po = selfp ? o : (1 - o);      // partner row's slot base
        float cu = __builtin_amdgcn_cosf((float)u * (1.0f / 1024.0f));
        float c2u = 2.0f * cu * cu - 1.0f;
        float hu = 2.0f + 2.0f * cu;
        #pragma unroll
        for (int j = 0; j < 4; ++j) {
            int vv = t + (j << 8);
            int vn = (1024 - vv) & 1023;
            float cv = __builtin_amdgcn_cosf((float)vv * (1.0f / 1024.0f));
            float c2v = 2.0f * cv * cv - 1.0f;
            float hv = 2.0f + 2.0f * cv;
            float grad = (2.0f - 2.0f * c2v) * hu * hu +
                         (2.0f - 2.0f * c2u) * hv * hv;
            float regs = 5.0f + 5.0f * grad;
            float G0x, G0y, G1x, G1y;
            #pragma unroll
            for (int c = 0; c < 2; ++c) {
                float2 a = resbuf[o * 2 + c][XS(vv)];
                float2 b = resbuf[po * 2 + c][XS(vn)];
                float Lx = 0.5f * (a.x + b.x), Ly = 0.5f * (a.y - b.y);
                float Fx = 0.5f * (a.y + b.y), Fy = -0.5f * (a.x - b.x);
                float inv = 1.0f / (Fx * Fx + Fy * Fy + regs);
                float nx = (Fx * Lx + Fy * Ly) * inv;   // conj(F)*L
                float ny = (Fx * Ly - Fy * Lx) * inv;
                if (c == 0) { G0x = nx; G0y = ny; } else { G1x = nx; G1y = ny; }
            }
            gi[j] = make_float2(G0x - G1y, G0y + G1x);
        }
    }
    __syncthreads();   // all resbuf reads complete; buffers reusable

    // inverse FFT along ky for row rows[grp]; disjoint scratch per group
    fft1024_reg<1>(gi, resbuf[grp], resbuf[2 + grp], t, false);
    const float isc = 1.0f / 1024.0f;
    float2* go = Wb + (((size_t)p << 20) + ((size_t)rows[grp] << 10));
    #pragma unroll
    for (int r = 0; r < 4; ++r)
        go[t + (r << 8)] = make_float2(gi[r].x * isc, gi[r].y * isc);
}

// ---------------------------------------------------------------------------
// Final inverse pass: block = 512 threads = 2 groups, each owning one of two
// adjacent output rows (y0+grp) read via dense float4 column loads of
// Wb[p][kx][y0..y0+1] (both groups load the same lines; L1 absorbs the dup;
// the unneeded half is discarded immediately -> no held registers).
// Per-group private 16KB ping-pong (32KB total). No occupancy pin (R4 spill
// lesson). Register row FFT, fused 1/N scale + fftshift + threshold + split
// + PER-WAVE argmax to private slots bm[ch*4096 + y*4 + wave-in-group].
// ---------------------------------------------------------------------------
__global__ __launch_bounds__(512) void ifft_final_kernel(
        const float2* __restrict__ Wd, float* __restrict__ psf,
        ull* __restrict__ bm) {
    __shared__ float2 buf[2][2][1024];
    int tid = threadIdx.x;
    int grp = tid >> 8;
    int t = tid & 255;
    int wvloc = (tid >> 6) & 3;        // wave index within group
    int p = blockIdx.x >> 9;           // grid 2048: 4 planes x 512
    int b0 = blockIdx.x & 511;
    int y0 = (((b0 & 7) << 6) | (b0 >> 3)) << 1;   // chunked swizzle, 2 rows
    int y = y0 + grp;
    const float2* g = Wd + (((size_t)p << 20) + y0);
    float2 v[4];
    #pragma unroll
    for (int m = 0; m < 4; ++m) {
        float4 qq = *(const float4*)&g[(size_t)(t + (m << 8)) << 10];
        v[m] = grp ? make_float2(qq.z, qq.w) : make_float2(qq.x, qq.y);
    }
    fft1024_reg<1>(v, buf[grp][0], buf[grp][1], t, false);

    const float sc = 1.0f / 1024.0f;
    int oy = (y + 512) & 1023;
    float* p0 = psf + (((size_t)(2 * p) << 20) + ((size_t)oy << 10));
    float* p1 = p0 + (1u << 20);
    ull e0 = 0, e1 = 0;
    #pragma unroll
    for (int r = 0; r < 4; ++r) {
        int k = t + (r << 8);
        float re = v[r].x * sc; re = (re < THRESH) ? 0.0f : re;
        float im = v[r].y * sc; im = (im < THRESH) ? 0.0f : im;
        int ox = (k + 512) & 1023;
        p0[ox] = re;
        p1[ox] = im;
        unsigned int idx = ((unsigned int)oy << 10) | (unsigned int)ox;
        ull c0 = ((ull)__float_as_uint(re) << 32) | (ull)(0xFFFFFFFFu - idx);
        ull c1 = ((ull)__float_as_uint(im) << 32) | (ull)(0xFFFFFFFFu - idx);
        e0 = c0 > e0 ? c0 : e0;
        e1 = c1 > e1 ? c1 : e1;
    }
    #pragma unroll
    for (int off = 32; off > 0; off >>= 1) {
        ull o0 = __shfl_down(e0, off);
        ull o1 = __shfl_down(e1, off);
        e0 = o0 > e0 ? o0 : e0;
        e1 = o1 > e1 ? o1 : e1;
    }
    if ((tid & 63) == 0) {
        bm[((size_t)(2 * p) << 12) + (y << 2) + wvloc] = e0;
        bm[((size_t)(2 * p + 1) << 12) + (y << 2) + wvloc] = e1;
    }
}

// ---------------------------------------------------------------------------
// Per-channel argmax finish (reduce 4096 per-wave maxima) + crop 41x41
// (dynamic_slice clamp semantics) + normalize. One block per channel.
// ---------------------------------------------------------------------------
__global__ __launch_bounds__(256) void crop_kernel(
        const float* __restrict__ psf, const ull* __restrict__ bm,
        float* __restrict__ out) {
    int c = blockIdx.x;
    __shared__ ull rmax[256];
    __shared__ float red[256];
    int tid = threadIdx.x;
    ull e = 0;
    for (int i = tid; i < 4096; i += 256) {
        ull v = bm[((size_t)c << 12) + i];
        e = v > e ? v : e;
    }
    rmax[tid] = e;
    __syncthreads();
    for (int s2 = 128; s2 > 0; s2 >>= 1) {
        if (tid < s2) { ull a = rmax[tid], b = rmax[tid + s2]; rmax[tid] = a > b ? a : b; }
        __syncthreads();
    }
    unsigned int bidx = 0xFFFFFFFFu - (unsigned int)(rmax[0] & 0xFFFFFFFFull);
    int row = (int)(bidx >> 10), col = (int)(bidx & 1023);
    int r0 = row - 20; if (r0 < 0) r0 = 0; if (r0 > SS - 41) r0 = SS - 41;
    int c0 = col - 20; if (c0 < 0) c0 = 0; if (c0 > SS - 41) c0 = SS - 41;
    const float* p = psf + ((size_t)c << 20);
    float local = 0.0f;
    for (int i = tid; i < 1681; i += 256) {
        int rr = i / 41, cc = i - rr * 41;
        local += p[(size_t)(r0 + rr) * SS + c0 + cc];
    }
    red[tid] = local;
    __syncthreads();
    for (int s2 = 128; s2 > 0; s2 >>= 1) {
        if (tid < s2) red[tid] += red[tid + s2];
        __syncthreads();
    }
    float inv = 1.0f / red[0];
    for (int i = tid; i < 1681; i += 256) {
        int rr = i / 41, cc = i - rr * 41;
        out[c * 1681 + i] = p[(size_t)(r0 + rr) * SS + c0 + cc] * inv;
    }
}

// ---------------------------------------------------------------------------
extern "C" void kernel_launch(void* const* d_in, const int* in_sizes, int n_in,
                              void* d_out, int out_size, void* d_ws,
                              size_t ws_size, hipStream_t stream) {
    const float* lms = (const float*)d_in[0];
    const float* fuse = (const float*)d_in[1];
    char* ws = (char*)d_ws;
    float2* Zf = (float2*)ws;                                   // 64 MB: 8 planes
    float2* Wb = (float2*)(ws + ((size_t)64 << 20));            // 32 MB: 4 planes
    float* psf = (float*)ws;                                    // 32 MB, reuses Zf
    ull* bm = (ull*)(ws + ((size_t)33 << 20));                  // 256 KB, dead Zf region
    float* outp = (float*)d_out;

    // 1. fused blur + pack + forward row-FFT -> Zf[c][y][cmap(kx)]
    blur_fft_kernel<<<8192, 256, 0, stream>>>(lms, fuse, Zf);
    // 2. fused col-FFT + Wiener + inverse-ky-FFT, 2 parallel groups/block
    fft2_wiener_kernel<<<2048, 512, 0, stream>>>(Zf, Wb);
    // 3. inverse kx-FFT (2 parallel rows/block) + shift/threshold/argmax
    ifft_final_kernel<<<2048, 512, 0, stream>>>(Wb, psf, bm);
    // 4. argmax finish + crop/normalize
    crop_kernel<<<8, 256, 0, stream>>>(psf, bm, outp);
}